// Round 1
// baseline (17.014 us; speedup 1.0000x reference)
//
#include <hip/hip_runtime.h>

// One 64-lane wave per row. Scan 64-element chunks from the front until any
// lane sees x>=0 (ballot), same from the back. Expected: exactly 1 chunk per
// end for random normal data -> ~512 B read per 8 KiB row (16x traffic cut).
__global__ void nby2_reverse_kernel(const float* __restrict__ x,
                                    float* __restrict__ out,
                                    int N, int D, int vrange) {
    const int gtid = blockIdx.x * blockDim.x + threadIdx.x;
    const int wave = gtid >> 6;          // wavefront = 64 on CDNA
    const int lane = threadIdx.x & 63;
    if (wave >= N) return;

    const float* __restrict__ row = x + (size_t)wave * (size_t)D;

    // ---- forward scan: first index with row[i] >= 0 ----
    int first = -1;
    for (int base = 0; base < D; base += 64) {
        const int idx = base + lane;
        const bool m = (idx < D) && (row[idx] >= 0.0f);
        const unsigned long long b = __ballot(m);
        if (b) { first = base + __builtin_ctzll(b); break; }
    }
    if (first < 0) {                     // no non-negative element in row
        if (lane == 0) out[wave] = 0.0f;
        return;
    }

    // ---- backward scan: last index with row[i] >= 0 ----
    int last = -1;
    int start = ((D - 1) / 64) * 64;     // last chunk base
    for (int base = start; base >= 0; base -= 64) {
        const int idx = base + lane;
        const bool m = (idx < D) && (row[idx] >= 0.0f);
        const unsigned long long b = __ballot(m);
        if (b) { last = base + 63 - __builtin_clzll(b); break; }
    }

    if (lane == 0) {
        const int bits = vrange >> 1;
        out[wave] = (float)(2 * bits - first - last - 1);
    }
}

extern "C" void kernel_launch(void* const* d_in, const int* in_sizes, int n_in,
                              void* d_out, int out_size, void* d_ws, size_t ws_size,
                              hipStream_t stream) {
    const float* x = (const float*)d_in[0];
    const int* vrange_p = (const int*)d_in[1];
    float* out = (float*)d_out;

    const int N = out_size;                       // 65536 rows
    const int D = in_sizes[0] / out_size;         // 2048 cols
    // vrange is a device scalar; but we know 2*bits == vrange numerically.
    // We must not dereference device memory on host: pass pointer-free math.
    // Since vrange == D for this problem per setup_inputs, derive on device
    // would need the pointer. Instead launch a tiny variant reading it.
    // Simpler: pass D as vrange surrogate is WRONG in general -> read on GPU.
    // We pass the pointer and let lane 0 load it once per wave? That's
    // redundant loads; instead use a trampoline kernel arg: vrange == in via
    // separate kernel reading the scalar. Cheapest correct option: have the
    // kernel read it directly.
    (void)vrange_p;

    const int waves_per_block = 4;                // 256 threads
    const int block = waves_per_block * 64;
    const int grid = (N + waves_per_block - 1) / waves_per_block;

    // Kernel variant that loads vrange from device memory (uniform scalar
    // load, cached in K$ after first wave).
    struct Launcher {
        static __global__ void run(const float* __restrict__ x,
                                   const int* __restrict__ vrange_p,
                                   float* __restrict__ out,
                                   int N, int D) {
            const int gtid = blockIdx.x * blockDim.x + threadIdx.x;
            const int wave = gtid >> 6;
            const int lane = threadIdx.x & 63;
            if (wave >= N) return;
            const float* __restrict__ row = x + (size_t)wave * (size_t)D;

            int first = -1;
            for (int base = 0; base < D; base += 64) {
                const int idx = base + lane;
                const bool m = (idx < D) && (row[idx] >= 0.0f);
                const unsigned long long b = __ballot(m);
                if (b) { first = base + __builtin_ctzll(b); break; }
            }
            if (first < 0) {
                if (lane == 0) out[wave] = 0.0f;
                return;
            }

            int last = -1;
            const int start = ((D - 1) / 64) * 64;
            for (int base = start; base >= 0; base -= 64) {
                const int idx = base + lane;
                const bool m = (idx < D) && (row[idx] >= 0.0f);
                const unsigned long long b = __ballot(m);
                if (b) { last = base + 63 - __builtin_clzll(b); break; }
            }

            if (lane == 0) {
                const int vr = *vrange_p;         // scalar, L2/K$-cached
                const int bits = vr >> 1;
                out[wave] = (float)(2 * bits - first - last - 1);
            }
        }
    };

    hipLaunchKernelGGL(Launcher::run, dim3(grid), dim3(block), 0, stream,
                       x, vrange_p, out, N, D);
}

// Round 2
// 12.663 us; speedup vs baseline: 1.3436x; 1.3436x over previous
//
#include <hip/hip_runtime.h>

// One 64-lane wave per row. Lanes 0..31 probe row[0..31], lanes 32..63 probe
// row[D-32..D-1] in a SINGLE load. One __ballot gives front mask (lo 32 bits)
// and back mask (hi 32 bits). P(all 32 N(0,1) samples < 0) = 2^-32, so the
// full-row fallback scan is effectively dead code kept for correctness.
__global__ void nby2_reverse_kernel(const float* __restrict__ x,
                                    const int* __restrict__ vrange_p,
                                    float* __restrict__ out,
                                    int N, int D) {
    const int wave = (blockIdx.x * blockDim.x + threadIdx.x) >> 6;
    const int lane = threadIdx.x & 63;
    if (wave >= N) return;

    const int vr = *vrange_p;            // uniform scalar load, issued early
    const float* __restrict__ row = x + (size_t)wave * (size_t)D;

    // Split probe: front 32 elements + back 32 elements, one load per lane.
    const int idx = (lane < 32) ? lane : (D - 64 + lane);
    const bool valid = (idx >= 0) && (idx < D);
    float v = -1.0f;
    if (valid) v = row[idx];
    const unsigned long long b = __ballot(valid && (v >= 0.0f));
    const unsigned lo = (unsigned)b;          // bit j  -> idx j
    const unsigned hi = (unsigned)(b >> 32);  // bit j  -> idx D-32+j

    int first, last;

    if (lo) {
        first = __builtin_ctz(lo);
    } else {
        // Rare: no non-negative in row[0..31]. Full forward scan.
        first = -1;
        for (int base = 0; base < D; base += 64) {
            const int i2 = base + lane;
            const bool m = (i2 < D) && (row[i2] >= 0.0f);
            const unsigned long long bb = __ballot(m);
            if (bb) { first = base + __builtin_ctzll(bb); break; }
        }
        if (first < 0) {                 // all-negative row
            if (lane == 0) out[wave] = 0.0f;
            return;
        }
    }

    if (hi) {
        last = D - 1 - __builtin_clz(hi);
    } else {
        // Rare: no non-negative in row[D-32..D-1]. Full backward scan.
        last = -1;
        const int start = ((D - 1) / 64) * 64;
        for (int base = start; base >= 0; base -= 64) {
            const int i2 = base + lane;
            const bool m = (i2 < D) && (row[i2] >= 0.0f);
            const unsigned long long bb = __ballot(m);
            if (bb) { last = base + 63 - __builtin_clzll(bb); break; }
        }
        // If we reach here with first >= 0, a non-negative exists, so last
        // is guaranteed found; no extra handling needed.
    }

    if (lane == 0) {
        const int bits = vr >> 1;
        out[wave] = (float)(2 * bits - first - last - 1);
    }
}

extern "C" void kernel_launch(void* const* d_in, const int* in_sizes, int n_in,
                              void* d_out, int out_size, void* d_ws, size_t ws_size,
                              hipStream_t stream) {
    const float* x = (const float*)d_in[0];
    const int* vrange_p = (const int*)d_in[1];
    float* out = (float*)d_out;

    const int N = out_size;                   // 65536 rows
    const int D = in_sizes[0] / out_size;     // 2048 cols

    const int waves_per_block = 4;            // 256 threads/block
    const int block = waves_per_block * 64;
    const int grid = (N + waves_per_block - 1) / waves_per_block;

    nby2_reverse_kernel<<<grid, block, 0, stream>>>(x, vrange_p, out, N, D);
}